// Round 5
// baseline (231.092 us; speedup 1.0000x reference)
//
#include <hip/hip_runtime.h>
#include <math.h>

#define REGION_MAX 116
#define EMB 768
#define EMB4 192          // float4s per row
#define DIM_D 182
#define DIM_H 218
#define DIM_W 182

typedef float v4f __attribute__((ext_vector_type(4)));
typedef int   v4i __attribute__((ext_vector_type(4)));

__device__ __forceinline__ int region_from_xyz(const float* __restrict__ vol,
                                               const float* M,
                                               float px, float py, float pz) {
    float fx = M[0] * px + M[1] * py + M[2]  * pz + M[3];
    float fy = M[4] * px + M[5] * py + M[6]  * pz + M[7];
    float fz = M[8] * px + M[9] * py + M[10] * pz + M[11];
    int x = (int)rintf(fx);   // round half-to-even, matches jnp.round
    int y = (int)rintf(fy);
    int z = (int)rintf(fz);
    bool inb = (x >= 0) & (x < DIM_D) & (y >= 0) & (y < DIM_H) &
               (z >= 0) & (z < DIM_W);
    int cx = min(max(x, 0), DIM_D - 1);
    int cy = min(max(y, 0), DIM_H - 1);
    int cz = min(max(z, 0), DIM_W - 1);
    int region = (int)vol[((size_t)cx * DIM_H + cy) * DIM_W + cz];  // trunc = astype(int32)
    // store premultiplied row offset in float4 units
    return ((inb && region >= 0 && region <= REGION_MAX) ? region : 0) * EMB4;
}

// --- phase 1: 4 points per thread; rid row-offsets -> d_ws ---
__global__ __launch_bounds__(128) void region_kernel(
    const float* __restrict__ centers,   // [P,3]
    const float* __restrict__ mri,       // [4,4]
    const float* __restrict__ aal,       // [4,4]
    const float* __restrict__ vol,       // [D,H,W]
    int* __restrict__ rid_out,           // [P] row offsets (rid*EMB4)
    int P4) {                            // P/4
    __shared__ float M[12];
    if (threadIdx.x == 0) {
        // M = inv(aal) @ mri, top 3 rows. Gauss-Jordan w/ partial pivoting.
        float a[4][8];
        for (int i = 0; i < 4; ++i)
            for (int j = 0; j < 4; ++j) {
                a[i][j]     = aal[i * 4 + j];
                a[i][j + 4] = (i == j) ? 1.0f : 0.0f;
            }
        for (int c = 0; c < 4; ++c) {
            int piv = c;
            float best = fabsf(a[c][c]);
            for (int r = c + 1; r < 4; ++r) {
                float v = fabsf(a[r][c]);
                if (v > best) { best = v; piv = r; }
            }
            if (piv != c)
                for (int j = 0; j < 8; ++j) {
                    float t = a[c][j]; a[c][j] = a[piv][j]; a[piv][j] = t;
                }
            float inv = 1.0f / a[c][c];
            for (int j = 0; j < 8; ++j) a[c][j] *= inv;
            for (int r = 0; r < 4; ++r) {
                if (r == c) continue;
                float f = a[r][c];
                for (int j = 0; j < 8; ++j) a[r][j] -= f * a[c][j];
            }
        }
        for (int i = 0; i < 3; ++i)
            for (int j = 0; j < 4; ++j) {
                float s = 0.0f;
                for (int k = 0; k < 4; ++k) s += a[i][4 + k] * mri[k * 4 + j];
                M[i * 4 + j] = s;
            }
    }
    __syncthreads();

    int t = blockIdx.x * blockDim.x + threadIdx.x;
    if (t >= P4) return;

    // 4 points = 12 floats = 3 aligned float4 loads
    const v4f* cv = (const v4f*)centers;
    v4f c0 = cv[t * 3 + 0];
    v4f c1 = cv[t * 3 + 1];
    v4f c2 = cv[t * 3 + 2];

    v4i r;
    r.x = region_from_xyz(vol, M, c0.x, c0.y, c0.z);
    r.y = region_from_xyz(vol, M, c0.w, c1.x, c1.y);
    r.z = region_from_xyz(vol, M, c1.z, c1.w, c2.x);
    r.w = region_from_xyz(vol, M, c2.y, c2.z, c2.w);
    ((v4i*)rid_out)[t] = r;
}

// --- phase 2: one wave per output row; rid is a wave-uniform scalar load ---
__global__ __launch_bounds__(256) void copy_kernel(
    const int* __restrict__ rid,         // [P] row offsets (rid*EMB4)
    const float* __restrict__ table,     // [117, EMB]
    float* __restrict__ out,             // [P, EMB]
    int P) {
    int row  = blockIdx.x * (blockDim.x >> 6) + (threadIdx.x >> 6);
    int lane = threadIdx.x & 63;
    if (row >= P) return;

    int off = __builtin_amdgcn_readfirstlane(rid[row]);  // scalar load path
    const v4f* __restrict__ src = (const v4f*)table + off;
    v4f* __restrict__ dst = (v4f*)out + (long)row * EMB4;

    v4f a0 = src[lane];
    v4f a1 = src[lane + 64];
    v4f a2 = src[lane + 128];
    __builtin_nontemporal_store(a0, &dst[lane]);
    __builtin_nontemporal_store(a1, &dst[lane + 64]);
    __builtin_nontemporal_store(a2, &dst[lane + 128]);
}

extern "C" void kernel_launch(void* const* d_in, const int* in_sizes, int n_in,
                              void* d_out, int out_size, void* d_ws, size_t ws_size,
                              hipStream_t stream) {
    const float* centers = (const float*)d_in[0];   // [B,N,3] f32
    const float* mri     = (const float*)d_in[1];   // [4,4]
    const float* aal     = (const float*)d_in[2];   // [4,4]
    const float* vol     = (const float*)d_in[3];   // [D,H,W]
    const float* table   = (const float*)d_in[4];   // [117,768]
    float* out = (float*)d_out;
    int*   rid = (int*)d_ws;                        // [P] ints

    int P  = in_sizes[0] / 3;                       // 65536
    int P4 = P / 4;                                 // 16384 (P divisible by 4)

    int blocks1 = (P4 + 127) / 128;                 // 128 blocks x 128 thr
    region_kernel<<<blocks1, 128, 0, stream>>>(centers, mri, aal, vol, rid, P4);

    int blocks2 = (P + 3) / 4;                      // 4 rows (waves) per block
    copy_kernel<<<blocks2, 256, 0, stream>>>(rid, table, out, P);
}

// Round 6
// 225.208 us; speedup vs baseline: 1.0261x; 1.0261x over previous
//
#include <hip/hip_runtime.h>
#include <math.h>

#define REGION_MAX 116
#define EMB 768
#define EMB4 192          // float4s per row
#define DIM_D 182
#define DIM_H 218
#define DIM_W 182

typedef float v4f __attribute__((ext_vector_type(4)));
typedef int   v4i __attribute__((ext_vector_type(4)));

__device__ __forceinline__ int region_from_xyz(const float* __restrict__ vol,
                                               const float* M,
                                               float px, float py, float pz) {
    float fx = M[0] * px + M[1] * py + M[2]  * pz + M[3];
    float fy = M[4] * px + M[5] * py + M[6]  * pz + M[7];
    float fz = M[8] * px + M[9] * py + M[10] * pz + M[11];
    int x = (int)rintf(fx);   // round half-to-even, matches jnp.round
    int y = (int)rintf(fy);
    int z = (int)rintf(fz);
    bool inb = (x >= 0) & (x < DIM_D) & (y >= 0) & (y < DIM_H) &
               (z >= 0) & (z < DIM_W);
    int cx = min(max(x, 0), DIM_D - 1);
    int cy = min(max(y, 0), DIM_H - 1);
    int cz = min(max(z, 0), DIM_W - 1);
    int region = (int)vol[((size_t)cx * DIM_H + cy) * DIM_W + cz];  // trunc = astype(int32)
    return (inb && region >= 0 && region <= REGION_MAX) ? region : 0;
}

// --- phase 1: 4 points per thread; rid -> d_ws ---
__global__ __launch_bounds__(128) void region_kernel(
    const float* __restrict__ centers,   // [P,3]
    const float* __restrict__ mri,       // [4,4]
    const float* __restrict__ aal,       // [4,4]
    const float* __restrict__ vol,       // [D,H,W]
    int* __restrict__ rid_out,           // [P]
    int P4) {                            // P/4
    __shared__ float M[12];
    if (threadIdx.x == 0) {
        // M = inv(aal) @ mri, top 3 rows. Gauss-Jordan w/ partial pivoting.
        float a[4][8];
        for (int i = 0; i < 4; ++i)
            for (int j = 0; j < 4; ++j) {
                a[i][j]     = aal[i * 4 + j];
                a[i][j + 4] = (i == j) ? 1.0f : 0.0f;
            }
        for (int c = 0; c < 4; ++c) {
            int piv = c;
            float best = fabsf(a[c][c]);
            for (int r = c + 1; r < 4; ++r) {
                float v = fabsf(a[r][c]);
                if (v > best) { best = v; piv = r; }
            }
            if (piv != c)
                for (int j = 0; j < 8; ++j) {
                    float t = a[c][j]; a[c][j] = a[piv][j]; a[piv][j] = t;
                }
            float inv = 1.0f / a[c][c];
            for (int j = 0; j < 8; ++j) a[c][j] *= inv;
            for (int r = 0; r < 4; ++r) {
                if (r == c) continue;
                float f = a[r][c];
                for (int j = 0; j < 8; ++j) a[r][j] -= f * a[c][j];
            }
        }
        for (int i = 0; i < 3; ++i)
            for (int j = 0; j < 4; ++j) {
                float s = 0.0f;
                for (int k = 0; k < 4; ++k) s += a[i][4 + k] * mri[k * 4 + j];
                M[i * 4 + j] = s;
            }
    }
    __syncthreads();

    int t = blockIdx.x * blockDim.x + threadIdx.x;
    if (t >= P4) return;

    // 4 points = 12 floats = 3 aligned float4 loads
    const v4f* cv = (const v4f*)centers;
    v4f c0 = cv[t * 3 + 0];
    v4f c1 = cv[t * 3 + 1];
    v4f c2 = cv[t * 3 + 2];

    v4i r;
    r.x = region_from_xyz(vol, M, c0.x, c0.y, c0.z);
    r.y = region_from_xyz(vol, M, c0.w, c1.x, c1.y);
    r.z = region_from_xyz(vol, M, c1.z, c1.w, c2.x);
    r.w = region_from_xyz(vol, M, c2.y, c2.z, c2.w);
    ((v4i*)rid_out)[t] = r;
}

// --- phase 2: flat streaming gather-copy, one thread per output float4 (R4) ---
__global__ __launch_bounds__(256) void copy_kernel(
    const int* __restrict__ rid,         // [P]
    const float* __restrict__ table,     // [117, EMB]
    float* __restrict__ out,             // [P, EMB]
    long total4) {                       // P * EMB4
    long i = (long)blockIdx.x * blockDim.x + threadIdx.x;
    if (i >= total4) return;
    long p = i / EMB4;                   // magic-mul div by 192
    int  c = (int)(i - p * EMB4);
    int  r = rid[p];                     // L1/L2 hit, shared by 192 threads
    const v4f* __restrict__ src = (const v4f*)(table) + (long)r * EMB4 + c;
    v4f v = *src;                        // table resident in L2 (359 KB)
    __builtin_nontemporal_store(v, ((v4f*)out) + i);
}

extern "C" void kernel_launch(void* const* d_in, const int* in_sizes, int n_in,
                              void* d_out, int out_size, void* d_ws, size_t ws_size,
                              hipStream_t stream) {
    const float* centers = (const float*)d_in[0];   // [B,N,3] f32
    const float* mri     = (const float*)d_in[1];   // [4,4]
    const float* aal     = (const float*)d_in[2];   // [4,4]
    const float* vol     = (const float*)d_in[3];   // [D,H,W]
    const float* table   = (const float*)d_in[4];   // [117,768]
    float* out = (float*)d_out;
    int*   rid = (int*)d_ws;                        // [P] ints

    int P  = in_sizes[0] / 3;                       // 65536
    int P4 = P / 4;                                 // 16384

    int blocks1 = (P4 + 127) / 128;
    region_kernel<<<blocks1, 128, 0, stream>>>(centers, mri, aal, vol, rid, P4);

    long total4 = (long)P * EMB4;                   // 12,582,912
    int blocks2 = (int)((total4 + 255) / 256);
    copy_kernel<<<blocks2, 256, 0, stream>>>(rid, table, out, total4);
}